// Round 4
// baseline (239.656 us; speedup 1.0000x reference)
//
#include <hip/hip_runtime.h>
#include <stdint.h>

// XOR chain = inclusive prefix-XOR along axis 0 of [S=4096, B=8192] int32.
// Round 18: SINGLE-VARIABLE test — NT stores -> plain stores.
// Evidence: R14 (register loads, 16 waves/CU) == R17 (LDS-DMA pipeline,
// 8 waves/CU) == ~82us with identical FETCH/WRITE => load path and occupancy
// exonerated. Common heavyweight phase: 132MB of __builtin_nontemporal_store.
// Harness fillBuffer does 524MB in 80us (6.7 TB/s) with plain stores =>
// HW write path is fine; NT flavor is the suspect (~3 TB/s => ~44us store
// phase, which closes the unexplained ~40us gap). This round: plain stores,
// everything else byte-identical to R17.
// Predict: dur 83.7 -> 60-66us if NT-slow (FETCH may rise due to LLC
// pollution); unchanged => stores exonerated, restructure reads next.

#define S 4096
#define B4 2048               // v4u column-groups per row
#define TPB 512
#define NCT (B4 / TPB)        // 4 coltiles
#define OUTER 64              // rows per chunk
#define NOUT (S / OUTER)      // 64 chunk-rows
#define NBLK (NOUT * NCT)     // 256 blocks, 1/CU, all resident
#define NWORDS (NOUT * B4)    // 128K dwords = 512 KB per table
#define POISON 0xAAAAAAAAu
#define STG 4                 // rows per stage
#define NSTG (OUTER / STG)    // 16 stages

typedef unsigned int v4u __attribute__((ext_vector_type(4)));
typedef unsigned long long u64;
typedef const __attribute__((address_space(1))) v4u* gp1_t;
typedef __attribute__((address_space(3))) v4u* lp3_t;

__device__ __forceinline__ bool valid(unsigned w) {
    return (w & 0x300u) == 0x100u;   // 0xAAAAAAAA poison and 0 both fail
}
__device__ __forceinline__ u64 repl(unsigned nib) {   // nibble -> 16 copies
    u64 m = nib;
    m |= m << 4; m |= m << 8; m |= m << 16; m |= m << 32;
    return m;
}

__global__ __launch_bounds__(TPB) void xor_plainst(
        const v4u* __restrict__ in, v4u* __restrict__ out,
        unsigned* __restrict__ ctl) {
    unsigned* agg = ctl + 64;
    unsigned* inc = agg + NWORDS;

    __shared__ v4u sh[2][STG][TPB];   // 64 KB, per-wave-private slabs

    const int tid   = (int)threadIdx.x;
    const int bid   = (int)blockIdx.x;
    const int ct    = bid & (NCT - 1);
    const int o     = bid >> 2;              // NCT = 4
    const int colg  = ct * TPB + tid;
    const int wbase = tid & ~63;             // wave-uniform lane base

    const v4u* p = in + (size_t)o * OUTER * B4 + colg;

    // ---- DMA-staged load of 64 rows: 16 stages x 4 rows, double-buffered.
    auto STAGE = [&](int srow, int buf) {
#pragma unroll
        for (int j = 0; j < STG; ++j)
            __builtin_amdgcn_global_load_lds(
                (gp1_t)(const void*)(p + (size_t)(srow + j) * B4),
                (lp3_t)(void*)&sh[buf][j][wbase], 16, 0, 0);
    };

    u64 q[4] = {0ull, 0ull, 0ull, 0ull};
    STAGE(0, 0);
    STAGE(STG, 1);
#pragma unroll
    for (int s = 0; s < NSTG; ++s) {
        if (s < NSTG - 1) asm volatile("s_waitcnt vmcnt(4)" ::: "memory");
        else              asm volatile("s_waitcnt vmcnt(0)" ::: "memory");
        const int buf = s & 1;
#pragma unroll
        for (int j = 0; j < STG; ++j) {
            v4u v = sh[buf][j][tid];
            unsigned n = (v.x & 1u) | ((v.y & 1u) << 1) |
                         ((v.z & 1u) << 2) | ((v.w & 1u) << 3);
            const int r = s * STG + j;
            q[r >> 4] ^= (u64)n << (4 * (r & 15));
        }
        // ds_reads fully retired before the DMA can overwrite this buffer
        asm volatile("s_waitcnt lgkmcnt(0)" ::: "memory");
        if (s + 2 < NSTG) STAGE((s + 2) * STG, buf);
    }

    // ---- Publish aggregate nibble (XOR of all 64 row-nibbles) ----
    u64 tt = q[0] ^ q[1] ^ q[2] ^ q[3];
    tt ^= tt >> 32; tt ^= tt >> 16; tt ^= tt >> 8; tt ^= tt >> 4;
    const unsigned myagg = (unsigned)tt & 0xFu;
    __hip_atomic_store(&agg[(size_t)o * B4 + colg], 0x100u | myagg,
                       __ATOMIC_RELAXED, __HIP_MEMORY_SCOPE_AGENT);

    // ---- Lookback: inc fast path + 16-wide batched agg polls ----
    unsigned ex = 0u;
    int k = o - 1;
    while (k >= 0) {
        unsigned iw = __hip_atomic_load(&inc[(size_t)k * B4 + colg],
                                        __ATOMIC_RELAXED,
                                        __HIP_MEMORY_SCOPE_AGENT);
        if (valid(iw)) { ex ^= (iw & 0xFu); break; }
        int n = (k + 1 < 16) ? (k + 1) : 16;
        unsigned a[16];
        for (int j = 0; j < n; ++j)
            a[j] = __hip_atomic_load(&agg[(size_t)(k - j) * B4 + colg],
                                     __ATOMIC_RELAXED,
                                     __HIP_MEMORY_SCOPE_AGENT);
        int consumed = 0;
        for (int j = 0; j < n; ++j) {
            if (valid(a[j])) { ex ^= (a[j] & 0xFu); ++consumed; }
            else break;
        }
        k -= consumed;
        if (consumed == 0) __builtin_amdgcn_s_sleep(1);
    }
    __hip_atomic_store(&inc[(size_t)o * B4 + colg], 0x100u | (ex ^ myagg),
                       __ATOMIC_RELAXED, __HIP_MEMORY_SCOPE_AGENT);

    // ---- Scan (4 shift-XOR steps per u64), seed, unpack, PLAIN store ----
    unsigned carry = ex;
    v4u* qo = out + (size_t)o * OUTER * B4 + colg;
#pragma unroll
    for (int kk = 0; kk < 4; ++kk) {
        u64 x = q[kk];
        x ^= x << 4; x ^= x << 8; x ^= x << 16; x ^= x << 32;  // prefix-XOR
        const u64 f = x ^ repl(carry);
        carry ^= (unsigned)(x >> 60) & 0xFu;
#pragma unroll
        for (int j = 0; j < 16; ++j) {
            const unsigned n = (unsigned)(f >> (4 * j)) & 0xFu;
            v4u ov = (v4u){n & 1u, (n >> 1) & 1u, (n >> 2) & 1u, (n >> 3) & 1u};
            qo[(size_t)(kk * 16 + j) * B4] = ov;      // plain store (was NT)
        }
    }
}

extern "C" void kernel_launch(void* const* d_in, const int* in_sizes, int n_in,
                              void* d_out, int out_size, void* d_ws, size_t ws_size,
                              hipStream_t stream) {
    const v4u* in = (const v4u*)d_in[0];
    v4u* out = (v4u*)d_out;
    unsigned* ctl = (unsigned*)d_ws;  // [0..63] ctl, then agg + inc (512 KB each)

    xor_plainst<<<NBLK, TPB, 0, stream>>>(in, out, ctl);
}